// Round 2
// baseline (401.536 us; speedup 1.0000x reference)
//
#include <hip/hip_runtime.h>
#include <stdint.h>

// ImpulseNoise (salt & pepper), bit-exact JAX threefry2x32 (partitionable path).
//
// R2 changes vs R1 (which measured 282 VALU instr/elem, VALUBusy ~98%):
//  - rotl via __builtin_amdgcn_alignbit -> 1 instr instead of shl+shr+or
//  - integer threshold compares replace the (>>9 | 0x3F800000) -1.0f float path
//    flip   <=> bits_f <= 386547199u   (m <= floor(0.09f * 2^23) = 754974)
//    salted <=> bits_s <= 0x800001FFu  (m <= 2^22, i.e. u <= 0.5)

__host__ __device__ constexpr uint32_t rotl32_c(uint32_t x, int r) {
    return (x << r) | (x >> (32 - r));
}

struct TF2 { uint32_t a, b; };

// constexpr version — used only at compile time to derive the two subkeys.
__host__ __device__ constexpr TF2 threefry2x32_c(uint32_t k0, uint32_t k1,
                                                 uint32_t x0, uint32_t x1) {
    const uint32_t ks0 = k0, ks1 = k1, ks2 = k0 ^ k1 ^ 0x1BD11BDAu;
    x0 += ks0; x1 += ks1;
    x0 += x1; x1 = rotl32_c(x1, 13); x1 ^= x0;
    x0 += x1; x1 = rotl32_c(x1, 15); x1 ^= x0;
    x0 += x1; x1 = rotl32_c(x1, 26); x1 ^= x0;
    x0 += x1; x1 = rotl32_c(x1,  6); x1 ^= x0;
    x0 += ks1; x1 += ks2 + 1u;
    x0 += x1; x1 = rotl32_c(x1, 17); x1 ^= x0;
    x0 += x1; x1 = rotl32_c(x1, 29); x1 ^= x0;
    x0 += x1; x1 = rotl32_c(x1, 16); x1 ^= x0;
    x0 += x1; x1 = rotl32_c(x1, 24); x1 ^= x0;
    x0 += ks2; x1 += ks0 + 2u;
    x0 += x1; x1 = rotl32_c(x1, 13); x1 ^= x0;
    x0 += x1; x1 = rotl32_c(x1, 15); x1 ^= x0;
    x0 += x1; x1 = rotl32_c(x1, 26); x1 ^= x0;
    x0 += x1; x1 = rotl32_c(x1,  6); x1 ^= x0;
    x0 += ks0; x1 += ks1 + 3u;
    x0 += x1; x1 = rotl32_c(x1, 17); x1 ^= x0;
    x0 += x1; x1 = rotl32_c(x1, 29); x1 ^= x0;
    x0 += x1; x1 = rotl32_c(x1, 16); x1 ^= x0;
    x0 += x1; x1 = rotl32_c(x1, 24); x1 ^= x0;
    x0 += ks1; x1 += ks2 + 4u;
    x0 += x1; x1 = rotl32_c(x1, 13); x1 ^= x0;
    x0 += x1; x1 = rotl32_c(x1, 15); x1 ^= x0;
    x0 += x1; x1 = rotl32_c(x1, 26); x1 ^= x0;
    x0 += x1; x1 = rotl32_c(x1,  6); x1 ^= x0;
    x0 += ks2; x1 += ks0 + 5u;
    return {x0, x1};
}

constexpr TF2 KFLIP = threefry2x32_c(0u, 42u, 0u, 0u);
constexpr TF2 KSALT = threefry2x32_c(0u, 42u, 0u, 1u);

// Integer-domain thresholds (see header comment).
constexpr uint32_t FLIP_MAX = (754974u << 9) | 511u;  // 386547199
constexpr uint32_t SALT_MAX = (4194304u << 9) | 511u; // 0x800001FF

// Device-optimized threefry: rotate = v_alignbit_b32 (1 instr).
__device__ __forceinline__ uint32_t rotl32_d(uint32_t x, int r) {
    return __builtin_amdgcn_alignbit(x, x, 32 - r);
}

template <uint32_t K0, uint32_t K1>
__device__ __forceinline__ uint32_t threefry_bits(uint32_t i) {
    constexpr uint32_t ks0 = K0, ks1 = K1, ks2 = K0 ^ K1 ^ 0x1BD11BDAu;
    uint32_t x0 = ks0;          // counter hi word is always 0
    uint32_t x1 = i + ks1;
    x0 += x1; x1 = rotl32_d(x1, 13); x1 ^= x0;
    x0 += x1; x1 = rotl32_d(x1, 15); x1 ^= x0;
    x0 += x1; x1 = rotl32_d(x1, 26); x1 ^= x0;
    x0 += x1; x1 = rotl32_d(x1,  6); x1 ^= x0;
    x0 += ks1; x1 += ks2 + 1u;
    x0 += x1; x1 = rotl32_d(x1, 17); x1 ^= x0;
    x0 += x1; x1 = rotl32_d(x1, 29); x1 ^= x0;
    x0 += x1; x1 = rotl32_d(x1, 16); x1 ^= x0;
    x0 += x1; x1 = rotl32_d(x1, 24); x1 ^= x0;
    x0 += ks2; x1 += ks0 + 2u;
    x0 += x1; x1 = rotl32_d(x1, 13); x1 ^= x0;
    x0 += x1; x1 = rotl32_d(x1, 15); x1 ^= x0;
    x0 += x1; x1 = rotl32_d(x1, 26); x1 ^= x0;
    x0 += x1; x1 = rotl32_d(x1,  6); x1 ^= x0;
    x0 += ks0; x1 += ks1 + 3u;
    x0 += x1; x1 = rotl32_d(x1, 17); x1 ^= x0;
    x0 += x1; x1 = rotl32_d(x1, 29); x1 ^= x0;
    x0 += x1; x1 = rotl32_d(x1, 16); x1 ^= x0;
    x0 += x1; x1 = rotl32_d(x1, 24); x1 ^= x0;
    x0 += ks1; x1 += ks2 + 4u;
    x0 += x1; x1 = rotl32_d(x1, 13); x1 ^= x0;
    x0 += x1; x1 = rotl32_d(x1, 15); x1 ^= x0;
    x0 += x1; x1 = rotl32_d(x1, 26); x1 ^= x0;
    x0 += x1; x1 = rotl32_d(x1,  6); x1 ^= x0;
    x0 += ks2; x1 += ks0 + 5u;
    return x0 ^ x1;
}

__global__ __launch_bounds__(256)
void ImpulseNoise_32040456028513_kernel(const float4* __restrict__ in,
                                        float4* __restrict__ out,
                                        unsigned n4) {
    unsigned tid = blockIdx.x * blockDim.x + threadIdx.x;
    if (tid >= n4) return;

    float4 v = in[tid];
    float r[4] = {v.x, v.y, v.z, v.w};
    const uint32_t base = tid << 2;

#pragma unroll
    for (int j = 0; j < 4; ++j) {
        const uint32_t i = base + (uint32_t)j;
        uint32_t bits_f = threefry_bits<KFLIP.a, KFLIP.b>(i);
        uint32_t bits_s = threefry_bits<KSALT.a, KSALT.b>(i);
        bool flip = (bits_f <= FLIP_MAX);
        float sp = (bits_s <= SALT_MAX) ? 1.0f : 0.0f;
        r[j] = flip ? sp : r[j];
    }

    out[tid] = make_float4(r[0], r[1], r[2], r[3]);
}

extern "C" void kernel_launch(void* const* d_in, const int* in_sizes, int n_in,
                              void* d_out, int out_size, void* d_ws, size_t ws_size,
                              hipStream_t stream) {
    const float4* in = (const float4*)d_in[0];
    float4* out = (float4*)d_out;
    unsigned n = (unsigned)in_sizes[0];   // 50331648, divisible by 4
    unsigned n4 = n >> 2;
    unsigned blocks = (n4 + 255u) / 256u;
    ImpulseNoise_32040456028513_kernel<<<blocks, 256, 0, stream>>>(in, out, n4);
}